// Round 11
// baseline (87.909 us; speedup 1.0000x reference)
//
#include <hip/hip_runtime.h>
#include <hip/hip_bf16.h>

typedef __attribute__((ext_vector_type(8))) short short8;
typedef __attribute__((ext_vector_type(4))) float f32x4;

#define NC    91
#define DM    64
#define CIN   128
#define NMOV  4206
#define MR    96
#define HP    68      // hbuf fp32 pitch
#define GP    92      // gram fp32 pitch
#define NT    512
#define NW    8

// d_ws bf16 weight offsets (in shorts)
#define W_EMBED 0
#define W_IN    8192
#define W_OUT   20480
#define W_FF1   24576
#define W_FF2   32768
#define W_FT    40960
#define W_TOTAL 49152

__constant__ int HEXOFF[NC] = {
  55,66,77,88,99,110,
  45,56,67,78,89,100,111,
  35,46,57,68,79,90,101,112,
  25,36,47,58,69,80,91,102,113,
  15,26,37,48,59,70,81,92,103,114,
  5,16,27,38,49,60,71,82,93,104,115,
  6,17,28,39,50,61,72,83,94,105,
  7,18,29,40,51,62,73,84,95,
  8,19,30,41,52,63,74,85,
  9,20,31,42,53,64,75,
  10,21,32,43,54,65
};

#define SWZ(row, col, PB) ((row)*(PB) + ((((((col)*2)>>4)) ^ ((row)&7)) << 4) + (((col)*2)&15))

__device__ __forceinline__ short f2bf(float f) {
  __hip_bfloat16 h = __float2bfloat16(f);
  return __builtin_bit_cast(short, h);
}
__device__ __forceinline__ float bflo(unsigned u){ return __builtin_bit_cast(float, u << 16); }
__device__ __forceinline__ float bfhi(unsigned u){ return __builtin_bit_cast(float, u & 0xffff0000u); }

__device__ __forceinline__ short8 ldfrag128(const short* buf, int row, int k0) {
  return *(const short8*)((const char*)buf + SWZ(row, k0, 128));
}
__device__ __forceinline__ short8 ldfrag256(const short* buf, int row, int k0) {
  return *(const short8*)((const char*)buf + SWZ(row, k0, 256));
}
__device__ __forceinline__ void stb16_128(short* buf, int row, int col, float v) {
  *(short*)((char*)buf + SWZ(row, col, 128)) = f2bf(v);
}
// B-fragment straight from global bf16 weights (row-major, K elems/row)
__device__ __forceinline__ short8 gfrag(const short* gw, int row, int K, int k0) {
  return *(const short8*)(gw + row*K + k0);
}

// 16-lane-group LayerNorm -> ab16 bf16 (swz PB=128)
__device__ __forceinline__ void ln_group(const float* hbuf, short* ab16,
                                         const float* gw, const float* gb,
                                         int wid, int lane) {
  const int sub = lane >> 4;
  const int l16 = lane & 15;
  const float4 g4 = *(const float4*)&gw[l16*4];
  const float4 b4 = *(const float4*)&gb[l16*4];
  for (int g = wid; g < 23; g += NW) {
    int i = g*4 + sub;
    if (i < NC) {
      float4 v = *(const float4*)&hbuf[i*HP + l16*4];
      float s  = (v.x + v.y) + (v.z + v.w);
      float sq = fmaf(v.x,v.x, fmaf(v.y,v.y, fmaf(v.z,v.z, v.w*v.w)));
      #pragma unroll
      for (int off = 1; off < 16; off <<= 1) {
        s  += __shfl_xor(s, off, 64);
        sq += __shfl_xor(sq, off, 64);
      }
      float m  = s * (1.0f/64.0f);
      float vr = sq * (1.0f/64.0f) - m*m;
      float rs = rsqrtf(vr + 1e-5f);
      short4 o;
      o.x = f2bf((v.x - m)*rs*g4.x + b4.x);
      o.y = f2bf((v.y - m)*rs*g4.y + b4.y);
      o.z = f2bf((v.z - m)*rs*g4.z + b4.z);
      o.w = f2bf((v.w - m)*rs*g4.w + b4.w);
      *(short4*)((char*)ab16 + i*128 + (((l16>>1) ^ (i&7))<<4) + (l16&1)*8) = o;
    }
  }
}

__global__ __launch_bounds__(256)
void prep_w(const float* __restrict__ embed_w, const float* __restrict__ in_w,
            const float* __restrict__ out_w, const float* __restrict__ ff1_w,
            const float* __restrict__ ff2_w, const float* __restrict__ from_w,
            const float* __restrict__ to_w, short* __restrict__ ws)
{
  int i = blockIdx.x*256 + threadIdx.x;
  if (i >= W_TOTAL) return;
  float v;
  if      (i < 8192)  v = embed_w[i];
  else if (i < 20480) v = in_w[i - 8192];
  else if (i < 24576) v = out_w[i - 20480];
  else if (i < 32768) v = ff1_w[i - 24576];
  else if (i < 40960) v = ff2_w[i - 32768];
  else if (i < 45056) v = from_w[i - 40960];
  else                v = to_w[i - 45056];
  ws[i] = f2bf(v);
}

__global__ __launch_bounds__(512, 4)
void policy_fused(
    const float* __restrict__ x,
    const float* __restrict__ embed_b, const float* __restrict__ pos,
    const float* __restrict__ in_b,  const float* __restrict__ out_b,
    const float* __restrict__ ln1_g, const float* __restrict__ ln1_b,
    const float* __restrict__ ln2_g, const float* __restrict__ ln2_b,
    const float* __restrict__ ff1_b, const float* __restrict__ ff2_b,
    const float* __restrict__ from_b, const float* __restrict__ to_b,
    const float* __restrict__ move_bias,
    const int* __restrict__ move_from, const int* __restrict__ move_to,
    const short* __restrict__ ws,
    float* __restrict__ out)
{
  __shared__ float Abuf[8736];       // 34944B: feats / qkv bf16 / f1 / G
  __shared__ float Bbuf[MR*HP];      // 26112B: hbuf ; F,T alias after P8
  __shared__ short ab16[MR*64];      // 12288B      => total 73344B, 2 blocks/CU

  const int tid  = threadIdx.x;
  const int lane = tid & 63;
  const int wid  = tid >> 6;
  const int l15  = lane & 15;
  const int kfr  = (lane >> 4) * 8;
  const int mfr  = (lane >> 4) * 4;
  const int b    = blockIdx.x;
  const float* xb = x + (size_t)b * (CIN*121);

  float* hbuf   = Bbuf;
  short* featsb = (short*)Abuf;                  // [96][128] bf16 swz PB=256
  short* qb = (short*)Abuf;                      // [4][91][16] bf16 (row 32B)
  short* kb = qb + 4*NC*16;
  short* vb = kb + 4*NC*16;
  short* f1 = (short*)Abuf;                      // [96][128] bf16 swz PB=256
  float* G  = Abuf;                              // [91][92] fp32

  // ---- P0: hex-gather feats -> bf16 ----
  for (int e = tid; e < 16*NC; e += NT) {
    int c0 = e / NC, i = e - c0*NC;
    float v[8];
    #pragma unroll
    for (int u = 0; u < 8; ++u) v[u] = xb[(c0*8 + u)*121 + HEXOFF[i]];
    short8 s8;
    #pragma unroll
    for (int u = 0; u < 8; ++u) s8[u] = f2bf(v[u]);
    *(short8*)((char*)featsb + i*256 + ((c0 ^ (i&7)) << 4)) = s8;
  }
  if (tid < 320) ((unsigned*)featsb)[5824 + tid] = 0;   // zero feats rows 91..95
  __syncthreads();

  // ---- P1: embed MFMA (K=128), B from ws ----
  for (int t = wid; t < 24; t += NW) {
    int mt = t >> 2, nt = t & 3;
    int ar = mt*16 + l15, br = nt*16 + l15;
    f32x4 acc = {0.f,0.f,0.f,0.f};
    #pragma unroll
    for (int kk = 0; kk < 4; ++kk) {
      short8 a = ldfrag256(featsb, ar, kk*32 + kfr);
      short8 w = gfrag(ws + W_EMBED, br, 128, kk*32 + kfr);
      acc = __builtin_amdgcn_mfma_f32_16x16x32_bf16(a, w, acc, 0, 0, 0);
    }
    int col = nt*16 + l15;
    float eb = embed_b[col];
    #pragma unroll
    for (int i2 = 0; i2 < 4; ++i2) {
      int m = mt*16 + mfr + i2;
      float p = (m < NC) ? pos[m*DM + col] : 0.f;
      hbuf[m*HP + col] = acc[i2] + eb + p;
    }
  }
  __syncthreads();

  // ---- P2: zero ab16 tail + LN1 -> ab16 ----
  if (tid < 160) ((unsigned*)ab16)[2912 + tid] = 0;
  ln_group(hbuf, ab16, ln1_g, ln1_b, wid, lane);
  __syncthreads();

  // ---- P3: qkv MFMA (N=192,K=64) -> q/k/v bf16 head layout ----
  for (int t = wid; t < 72; t += NW) {
    int mt = t / 12, nt = t - mt*12;
    int ar = mt*16 + l15, br = nt*16 + l15;
    f32x4 acc = {0.f,0.f,0.f,0.f};
    #pragma unroll
    for (int kk = 0; kk < 2; ++kk) {
      short8 a = ldfrag128(ab16, ar, kk*32 + kfr);
      short8 w = gfrag(ws + W_IN, br, 64, kk*32 + kfr);
      acc = __builtin_amdgcn_mfma_f32_16x16x32_bf16(a, w, acc, 0, 0, 0);
    }
    int col = nt*16 + l15;
    float bia = in_b[col];
    int hl = (col & 63) >> 4;
    int d  = col & 15;
    short* dst = (col < 64) ? qb : ((col < 128) ? kb : vb);
    #pragma unroll
    for (int i2 = 0; i2 < 4; ++i2) {
      int m = mt*16 + mfr + i2;
      if (m < NC) dst[(hl*NC + m)*16 + d] = f2bf(acc[i2] + bia);
    }
  }
  __syncthreads();

  // ---- P4: attention, 1 thread per (h,i), bf16 k/v via shift-cvt ----
  if (tid < 4*NC) {
    const int h = tid / NC;
    const int i = tid - h*NC;
    const float CS = 0.25f * 1.4426950408889634f;
    const unsigned* qp = (const unsigned*)(qb + (h*NC + i)*16);
    uint4 qv0 = *(const uint4*)qp, qv1 = *(const uint4*)(qp + 4);
    float q0=bflo(qv0.x)*CS, q1=bfhi(qv0.x)*CS, q2f=bflo(qv0.y)*CS, q3=bfhi(qv0.y)*CS,
          q4=bflo(qv0.z)*CS, q5=bfhi(qv0.z)*CS, q6=bflo(qv0.w)*CS, q7=bfhi(qv0.w)*CS,
          q8=bflo(qv1.x)*CS, q9=bfhi(qv1.x)*CS, qA=bflo(qv1.y)*CS, qB=bfhi(qv1.y)*CS,
          qC=bflo(qv1.z)*CS, qD=bfhi(qv1.z)*CS, qE=bflo(qv1.w)*CS, qF=bfhi(qv1.w)*CS;
    const unsigned* kp = (const unsigned*)(kb + h*NC*16);
    const unsigned* vp = (const unsigned*)(vb + h*NC*16);
    float4 oa = {0,0,0,0}, obv = {0,0,0,0}, ocv = {0,0,0,0}, odv = {0,0,0,0};
    float lrun = 0.0f;
    for (int j = 0; j < NC; ++j) {
      uint4 k0v = *(const uint4*)(kp + j*8);
      uint4 k1v = *(const uint4*)(kp + j*8 + 4);
      float t0 = fmaf(q1, bfhi(k0v.x), q0*bflo(k0v.x));
      t0 = fmaf(q3, bfhi(k0v.y), fmaf(q2f, bflo(k0v.y), t0));
      float t1 = fmaf(q5, bfhi(k0v.z), q4*bflo(k0v.z));
      t1 = fmaf(q7, bfhi(k0v.w), fmaf(q6, bflo(k0v.w), t1));
      float t2 = fmaf(q9, bfhi(k1v.x), q8*bflo(k1v.x));
      t2 = fmaf(qB, bfhi(k1v.y), fmaf(qA, bflo(k1v.y), t2));
      float t3 = fmaf(qD, bfhi(k1v.z), qC*bflo(k1v.z));
      t3 = fmaf(qF, bfhi(k1v.w), fmaf(qE, bflo(k1v.w), t3));
      float pw = exp2f((t0+t1)+(t2+t3));   // no-max softmax (scores bounded)
      lrun += pw;
      uint4 v0v = *(const uint4*)(vp + j*8);
      uint4 v1v = *(const uint4*)(vp + j*8 + 4);
      oa.x  = fmaf(pw, bflo(v0v.x), oa.x);  oa.y  = fmaf(pw, bfhi(v0v.x), oa.y);
      oa.z  = fmaf(pw, bflo(v0v.y), oa.z);  oa.w  = fmaf(pw, bfhi(v0v.y), oa.w);
      obv.x = fmaf(pw, bflo(v0v.z), obv.x); obv.y = fmaf(pw, bfhi(v0v.z), obv.y);
      obv.z = fmaf(pw, bflo(v0v.w), obv.z); obv.w = fmaf(pw, bfhi(v0v.w), obv.w);
      ocv.x = fmaf(pw, bflo(v1v.x), ocv.x); ocv.y = fmaf(pw, bfhi(v1v.x), ocv.y);
      ocv.z = fmaf(pw, bflo(v1v.y), ocv.z); ocv.w = fmaf(pw, bfhi(v1v.y), ocv.w);
      odv.x = fmaf(pw, bflo(v1v.z), odv.x); odv.y = fmaf(pw, bfhi(v1v.z), odv.y);
      odv.z = fmaf(pw, bflo(v1v.w), odv.z); odv.w = fmaf(pw, bfhi(v1v.w), odv.w);
    }
    float inv = 1.0f / lrun;
    short8 ow0, ow1;
    ow0[0]=f2bf(oa.x*inv);  ow0[1]=f2bf(oa.y*inv);  ow0[2]=f2bf(oa.z*inv);  ow0[3]=f2bf(oa.w*inv);
    ow0[4]=f2bf(obv.x*inv); ow0[5]=f2bf(obv.y*inv); ow0[6]=f2bf(obv.z*inv); ow0[7]=f2bf(obv.w*inv);
    ow1[0]=f2bf(ocv.x*inv); ow1[1]=f2bf(ocv.y*inv); ow1[2]=f2bf(ocv.z*inv); ow1[3]=f2bf(ocv.w*inv);
    ow1[4]=f2bf(odv.x*inv); ow1[5]=f2bf(odv.y*inv); ow1[6]=f2bf(odv.z*inv); ow1[7]=f2bf(odv.w*inv);
    *(short8*)((char*)ab16 + SWZ(i, h*16,     128)) = ow0;
    *(short8*)((char*)ab16 + SWZ(i, h*16 + 8, 128)) = ow1;
  }
  __syncthreads();

  // ---- P5: out-proj MFMA: hbuf += o @ out_w^T + out_b ----
  for (int t = wid; t < 24; t += NW) {
    int mt = t >> 2, nt = t & 3;
    int ar = mt*16 + l15, br = nt*16 + l15;
    f32x4 acc = {0.f,0.f,0.f,0.f};
    #pragma unroll
    for (int kk = 0; kk < 2; ++kk) {
      short8 a = ldfrag128(ab16, ar, kk*32 + kfr);
      short8 w = gfrag(ws + W_OUT, br, 64, kk*32 + kfr);
      acc = __builtin_amdgcn_mfma_f32_16x16x32_bf16(a, w, acc, 0, 0, 0);
    }
    int col = nt*16 + l15;
    float ob = out_b[col];
    #pragma unroll
    for (int i2 = 0; i2 < 4; ++i2) {
      int m = mt*16 + mfr + i2;
      hbuf[m*HP + col] += acc[i2] + ob;
    }
  }
  __syncthreads();

  // ---- P6: LN2 -> ab16 ----
  ln_group(hbuf, ab16, ln2_g, ln2_b, wid, lane);
  __syncthreads();

  // ---- P7: ff1 MFMA (N=128,K=64) -> f1 bf16 ----
  for (int t = wid; t < 48; t += NW) {
    int mt = t >> 3, nt = t & 7;
    int ar = mt*16 + l15, br = nt*16 + l15;
    f32x4 acc = {0.f,0.f,0.f,0.f};
    #pragma unroll
    for (int kk = 0; kk < 2; ++kk) {
      short8 a = ldfrag128(ab16, ar, kk*32 + kfr);
      short8 w = gfrag(ws + W_FF1, br, 64, kk*32 + kfr);
      acc = __builtin_amdgcn_mfma_f32_16x16x32_bf16(a, w, acc, 0, 0, 0);
    }
    int col = nt*16 + l15;
    float bia = ff1_b[col];
    #pragma unroll
    for (int i2 = 0; i2 < 4; ++i2) {
      int m = mt*16 + mfr + i2;
      *(short*)((char*)f1 + SWZ(m, col, 256)) = f2bf(fmaxf(acc[i2] + bia, 0.f));
    }
  }
  __syncthreads();

  // ---- P8: ff2 MFMA (K=128): ab16 = bf16(hbuf + f1@W^T + b) ----
  for (int t = wid; t < 24; t += NW) {
    int mt = t >> 2, nt = t & 3;
    int ar = mt*16 + l15, br = nt*16 + l15;
    f32x4 acc = {0.f,0.f,0.f,0.f};
    #pragma unroll
    for (int kk = 0; kk < 4; ++kk) {
      short8 a = ldfrag256(f1, ar, kk*32 + kfr);
      short8 w = gfrag(ws + W_FF2, br, 128, kk*32 + kfr);
      acc = __builtin_amdgcn_mfma_f32_16x16x32_bf16(a, w, acc, 0, 0, 0);
    }
    int col = nt*16 + l15;
    float bia = ff2_b[col];
    #pragma unroll
    for (int i2 = 0; i2 < 4; ++i2) {
      int m = mt*16 + mfr + i2;
      stb16_128(ab16, m, col, hbuf[m*HP + col] + acc[i2] + bia);
    }
  }
  __syncthreads();

  // ---- P9: from/to MFMA (N=128,K=64) -> F,T bf16 (alias hbuf region) ----
  short* Fb = (short*)Bbuf;
  short* Tb = (short*)Bbuf + 6144;
  for (int t = wid; t < 48; t += NW) {
    int mt = t >> 3, nt = t & 7;
    int ar = mt*16 + l15, br = nt*16 + l15;
    f32x4 acc = {0.f,0.f,0.f,0.f};
    #pragma unroll
    for (int kk = 0; kk < 2; ++kk) {
      short8 a = ldfrag128(ab16, ar, kk*32 + kfr);
      short8 w = gfrag(ws + W_FT, br, 64, kk*32 + kfr);
      acc = __builtin_amdgcn_mfma_f32_16x16x32_bf16(a, w, acc, 0, 0, 0);
    }
    int col = nt*16 + l15;
    if (nt < 4) {
      float bia = from_b[col];
      #pragma unroll
      for (int i2 = 0; i2 < 4; ++i2)
        stb16_128(Fb, mt*16 + mfr + i2, col, acc[i2] + bia);
    } else {
      int c2 = col - 64;
      float bia = to_b[c2];
      #pragma unroll
      for (int i2 = 0; i2 < 4; ++i2)
        stb16_128(Tb, mt*16 + mfr + i2, c2, acc[i2] + bia);
    }
  }
  __syncthreads();

  // ---- P10: gram MFMA: G = F @ T^T -> Abuf (pitch 92; col clamped) ----
  for (int t = wid; t < 36; t += NW) {
    int mt = t / 6, nt = t - mt*6;
    int ar = mt*16 + l15, br = nt*16 + l15;
    f32x4 acc = {0.f,0.f,0.f,0.f};
    #pragma unroll
    for (int kk = 0; kk < 2; ++kk) {
      short8 a = ldfrag128(Fb, ar, kk*32 + kfr);
      short8 w = ldfrag128(Tb, br, kk*32 + kfr);
      acc = __builtin_amdgcn_mfma_f32_16x16x32_bf16(a, w, acc, 0, 0, 0);
    }
    int col = nt*16 + l15;
    if (col < GP) {
      #pragma unroll
      for (int i2 = 0; i2 < 4; ++i2) {
        int m = mt*16 + mfr + i2;
        if (m < NC) G[m*GP + col] = acc[i2];
      }
    }
  }
  __syncthreads();

  // ---- P11: logits gather ----
  {
    float* ob = out + (size_t)b * NMOV;
    for (int m = tid; m < NMOV; m += NT) {
      ob[m] = G[move_from[m]*GP + move_to[m]] + move_bias[m];
    }
  }
}

extern "C" void kernel_launch(void* const* d_in, const int* in_sizes, int n_in,
                              void* d_out, int out_size, void* d_ws, size_t ws_size,
                              hipStream_t stream) {
  const float* x        = (const float*)d_in[0];
  const float* embed_w  = (const float*)d_in[1];
  const float* embed_b  = (const float*)d_in[2];
  const float* pos      = (const float*)d_in[3];
  const float* in_w     = (const float*)d_in[4];
  const float* in_b     = (const float*)d_in[5];
  const float* out_w    = (const float*)d_in[6];
  const float* out_b    = (const float*)d_in[7];
  const float* ln1_g    = (const float*)d_in[8];
  const float* ln1_b    = (const float*)d_in[9];
  const float* ln2_g    = (const float*)d_in[10];
  const float* ln2_b    = (const float*)d_in[11];
  const float* ff1_w    = (const float*)d_in[12];
  const float* ff1_b    = (const float*)d_in[13];
  const float* ff2_w    = (const float*)d_in[14];
  const float* ff2_b    = (const float*)d_in[15];
  const float* from_w   = (const float*)d_in[16];
  const float* from_b   = (const float*)d_in[17];
  const float* to_w     = (const float*)d_in[18];
  const float* to_b     = (const float*)d_in[19];
  const float* move_bias= (const float*)d_in[20];
  const int*   move_from= (const int*)d_in[21];
  const int*   move_to  = (const int*)d_in[22];

  short* wsb = (short*)d_ws;
  prep_w<<<dim3((W_TOTAL + 255)/256), dim3(256), 0, stream>>>(
      embed_w, in_w, out_w, ff1_w, ff2_w, from_w, to_w, wsb);

  int B = in_sizes[0] / (CIN * 121);
  policy_fused<<<dim3(B), dim3(NT), 0, stream>>>(
      x, embed_b, pos, in_b, out_b,
      ln1_g, ln1_b, ln2_g, ln2_b, ff1_b, ff2_b,
      from_b, to_b, move_bias, move_from, move_to,
      (const short*)wsb, (float*)d_out);
}

// Round 12
// 52.982 us; speedup vs baseline: 1.6592x; 1.6592x over previous
//
#include <hip/hip_runtime.h>
#include <hip/hip_bf16.h>

typedef __attribute__((ext_vector_type(8))) short short8;
typedef __attribute__((ext_vector_type(4))) float f32x4;

#define NC    91
#define DM    64
#define CIN   128
#define NMOV  4206
#define MR    96
#define HP    68      // hbuf fp32 pitch
#define NT    1024
#define NW    16
#define PP    392     // P_all bf16 pitch (shorts): 4 heads * 96 + 8 pad
#define VTP   104     // vT pitch (j dim, shorts)

// d_ws bf16 weight offsets (in shorts)
#define W_EMBED 0
#define W_IN    8192
#define W_OUT   20480
#define W_FF1   24576
#define W_FF2   32768
#define W_FT    40960
#define W_TOTAL 49152

__constant__ int HEXOFF[NC] = {
  55,66,77,88,99,110,
  45,56,67,78,89,100,111,
  35,46,57,68,79,90,101,112,
  25,36,47,58,69,80,91,102,113,
  15,26,37,48,59,70,81,92,103,114,
  5,16,27,38,49,60,71,82,93,104,115,
  6,17,28,39,50,61,72,83,94,105,
  7,18,29,40,51,62,73,84,95,
  8,19,30,41,52,63,74,85,
  9,20,31,42,53,64,75,
  10,21,32,43,54,65
};

#define SWZ(row, col, PB) ((row)*(PB) + ((((((col)*2)>>4)) ^ ((row)&7)) << 4) + (((col)*2)&15))

__device__ __forceinline__ short f2bf(float f) {
  __hip_bfloat16 h = __float2bfloat16(f);
  return __builtin_bit_cast(short, h);
}
__device__ __forceinline__ float bfs(short v) {
  return __builtin_bit_cast(float, ((unsigned)(unsigned short)v) << 16);
}
__device__ __forceinline__ float bflo(unsigned u){ return __builtin_bit_cast(float, u << 16); }
__device__ __forceinline__ float bfhi(unsigned u){ return __builtin_bit_cast(float, u & 0xffff0000u); }

__device__ __forceinline__ short8 ldfrag128(const short* buf, int row, int k0) {
  return *(const short8*)((const char*)buf + SWZ(row, k0, 128));
}
__device__ __forceinline__ short8 ldfrag256(const short* buf, int row, int k0) {
  return *(const short8*)((const char*)buf + SWZ(row, k0, 256));
}
__device__ __forceinline__ void stb16_128(short* buf, int row, int col, float v) {
  *(short*)((char*)buf + SWZ(row, col, 128)) = f2bf(v);
}
// 16B copy from bf16 ws (row-major, K cols) into swizzled LDS slot
__device__ __forceinline__ void cp8_swz(short* dst, int PB, const short* src, int r, int c8, int K) {
  short8 v = *(const short8*)(src + r*K + c8*8);
  *(short8*)((char*)dst + r*PB + ((c8 ^ (r&7)) << 4)) = v;
}

// 16-lane-group LayerNorm -> ab16 bf16 (swz PB=128)
__device__ __forceinline__ void ln_group(const float* hbuf, short* ab16,
                                         const float* gw, const float* gb,
                                         int wid, int lane) {
  const int sub = lane >> 4;
  const int l16 = lane & 15;
  const float4 g4 = *(const float4*)&gw[l16*4];
  const float4 b4 = *(const float4*)&gb[l16*4];
  for (int g = wid; g < 23; g += NW) {
    int i = g*4 + sub;
    if (i < NC) {
      float4 v = *(const float4*)&hbuf[i*HP + l16*4];
      float s  = (v.x + v.y) + (v.z + v.w);
      float sq = fmaf(v.x,v.x, fmaf(v.y,v.y, fmaf(v.z,v.z, v.w*v.w)));
      #pragma unroll
      for (int off = 1; off < 16; off <<= 1) {
        s  += __shfl_xor(s, off, 64);
        sq += __shfl_xor(sq, off, 64);
      }
      float m  = s * (1.0f/64.0f);
      float vr = sq * (1.0f/64.0f) - m*m;
      float rs = rsqrtf(vr + 1e-5f);
      short4 o;
      o.x = f2bf((v.x - m)*rs*g4.x + b4.x);
      o.y = f2bf((v.y - m)*rs*g4.y + b4.y);
      o.z = f2bf((v.z - m)*rs*g4.z + b4.z);
      o.w = f2bf((v.w - m)*rs*g4.w + b4.w);
      *(short4*)((char*)ab16 + i*128 + (((l16>>1) ^ (i&7))<<4) + (l16&1)*8) = o;
    }
  }
}

__global__ __launch_bounds__(256)
void prep_w(const float* __restrict__ embed_w, const float* __restrict__ in_w,
            const float* __restrict__ out_w, const float* __restrict__ ff1_w,
            const float* __restrict__ ff2_w, const float* __restrict__ from_w,
            const float* __restrict__ to_w, short* __restrict__ ws)
{
  int i = blockIdx.x*256 + threadIdx.x;
  if (i >= W_TOTAL) return;
  float v;
  if      (i < 8192)  v = embed_w[i];
  else if (i < 20480) v = in_w[i - 8192];
  else if (i < 24576) v = out_w[i - 20480];
  else if (i < 32768) v = ff1_w[i - 24576];
  else if (i < 40960) v = ff2_w[i - 32768];
  else if (i < 45056) v = from_w[i - 40960];
  else                v = to_w[i - 45056];
  ws[i] = f2bf(v);
}

__global__ __launch_bounds__(1024, 1)
void policy_fused(
    const float* __restrict__ x,
    const float* __restrict__ embed_b, const float* __restrict__ pos,
    const float* __restrict__ in_b,  const float* __restrict__ out_b,
    const float* __restrict__ ln1_g, const float* __restrict__ ln1_b,
    const float* __restrict__ ln2_g, const float* __restrict__ ln2_b,
    const float* __restrict__ ff1_b, const float* __restrict__ ff2_b,
    const float* __restrict__ from_b, const float* __restrict__ to_b,
    const float* __restrict__ move_bias,
    const int* __restrict__ move_from, const int* __restrict__ move_to,
    const short* __restrict__ ws,
    float* __restrict__ out)
{
  __shared__ float arena[18816];     // 75264B: feats / qkv fp32 / P_all / G+f1
  __shared__ float hbuf[MR*HP];      // 26112B: residual h ; F,T alias after P8
  __shared__ short ab16[MR*64];      // 12288B: LN out / attn out
  __shared__ short wAll[20480];      // 40960B: staged weights / q,k,vT
  __shared__ float linv[384];        // 1536B       => total 156160B

  const int tid  = threadIdx.x;
  const int lane = tid & 63;
  const int wid  = tid >> 6;
  const int l15  = lane & 15;
  const int kfr  = (lane >> 4) * 8;
  const int mfr  = (lane >> 4) * 4;
  const int b    = blockIdx.x;
  const float* xb = x + (size_t)b * (CIN*121);

  short* featsb = (short*)arena;           // [96][128] bf16 swz PB=256
  float* qkv    = arena;                   // [96][196] fp32 (after feats dead)
  short* pall   = (short*)arena;           // [96][PP] bf16 (after qkv dead)
  float* G      = arena;                   // [96][96] fp32 (after pall dead)
  short* f1     = (short*)arena + 18432;   // [96][128] bf16 swz PB=256 (bytes 36864..61440)
  short* qb     = wAll;                    // [4][96][16] bf16 plain
  short* kb     = wAll + 6144;
  short* vtb    = wAll + 12288;            // [4][16][VTP] bf16 (V^T)

  // ---- P0: hex-gather feats -> bf16 ; stage embed_w + in_w from ws ----
  for (int e = tid; e < 16*NC; e += NT) {
    int c0 = e / NC, i = e - c0*NC;
    float v[8];
    #pragma unroll
    for (int u = 0; u < 8; ++u) v[u] = xb[(c0*8 + u)*121 + HEXOFF[i]];
    short8 s8;
    #pragma unroll
    for (int u = 0; u < 8; ++u) s8[u] = f2bf(v[u]);
    *(short8*)((char*)featsb + i*256 + ((c0 ^ (i&7)) << 4)) = s8;
  }
  if (tid < 320) ((unsigned*)featsb)[5824 + tid] = 0;   // zero feats rows 91..95
  for (int e = tid; e < 1024; e += NT) {                // embed_w [64][128] -> wAll[0..] swz256
    int r = e >> 4, c8 = e & 15;
    cp8_swz(wAll, 256, ws + W_EMBED, r, c8, 128);
  }
  for (int e = tid; e < 1536; e += NT) {                // in_w [192][64] -> wAll[8192..] swz128
    int r = e >> 3, c8 = e & 7;
    cp8_swz(wAll + 8192, 128, ws + W_IN, r, c8, 64);
  }
  __syncthreads();

  // ---- P1: embed MFMA (K=128) -> hbuf ----
  for (int t = wid; t < 24; t += NW) {
    int mt = t >> 2, nt = t & 3;
    int ar = mt*16 + l15, br = nt*16 + l15;
    f32x4 acc = {0.f,0.f,0.f,0.f};
    #pragma unroll
    for (int kk = 0; kk < 4; ++kk) {
      short8 a = ldfrag256(featsb, ar, kk*32 + kfr);
      short8 w = ldfrag256(wAll,   br, kk*32 + kfr);
      acc = __builtin_amdgcn_mfma_f32_16x16x32_bf16(a, w, acc, 0, 0, 0);
    }
    int col = nt*16 + l15;
    float eb = embed_b[col];
    #pragma unroll
    for (int i2 = 0; i2 < 4; ++i2) {
      int m = mt*16 + mfr + i2;
      float p = (m < NC) ? pos[m*DM + col] : 0.f;
      hbuf[m*HP + col] = acc[i2] + eb + p;
    }
  }
  __syncthreads();

  // ---- P2: zero ab16 tail + LN1 -> ab16 ----
  if (tid < 160) ((unsigned*)ab16)[2912 + tid] = 0;
  ln_group(hbuf, ab16, ln1_g, ln1_b, wid, lane);
  __syncthreads();

  // ---- P3: qkv MFMA (N=192,K=64) -> qkv fp32 arena pitch 196 ----
  for (int t = wid; t < 72; t += NW) {
    int mt = t / 12, nt = t - mt*12;
    int ar = mt*16 + l15, br = nt*16 + l15;
    f32x4 acc = {0.f,0.f,0.f,0.f};
    #pragma unroll
    for (int kk = 0; kk < 2; ++kk) {
      short8 a = ldfrag128(ab16,        ar, kk*32 + kfr);
      short8 w = ldfrag128(wAll + 8192, br, kk*32 + kfr);
      acc = __builtin_amdgcn_mfma_f32_16x16x32_bf16(a, w, acc, 0, 0, 0);
    }
    int col = nt*16 + l15;
    float bia = in_b[col];
    #pragma unroll
    for (int i2 = 0; i2 < 4; ++i2)
      qkv[(mt*16 + mfr + i2)*196 + col] = acc[i2] + bia;
  }
  __syncthreads();

  // ---- P3b: qkv fp32 -> q(*CS),k bf16 head-layout + vT ; zero tails ----
  {
    const float CS = 0.25f * 1.4426950408889634f;
    if (tid < 4*NC) {
      int h = tid / NC, i = tid - h*NC;
      const float* src = &qkv[i*196];
      short8 qs, ks;
      #pragma unroll
      for (int d = 0; d < 8; ++d) { qs[d] = f2bf(src[h*16 + d] * CS); ks[d] = f2bf(src[64 + h*16 + d]); }
      short8 qs2, ks2;
      #pragma unroll
      for (int d = 0; d < 8; ++d) { qs2[d] = f2bf(src[h*16 + 8 + d] * CS); ks2[d] = f2bf(src[64 + h*16 + 8 + d]); }
      *(short8*)(qb + (h*96 + i)*16)     = qs;
      *(short8*)(qb + (h*96 + i)*16 + 8) = qs2;
      *(short8*)(kb + (h*96 + i)*16)     = ks;
      *(short8*)(kb + (h*96 + i)*16 + 8) = ks2;
      #pragma unroll
      for (int d = 0; d < 16; ++d)
        vtb[(h*16 + d)*VTP + i] = f2bf(src[128 + h*16 + d]);
    }
    // zero q,k rows 91..95 (u32) and vT cols 91..103 (short)
    for (int e = tid; e < 160; e += NT) {
      int h = e / 40, off = e - h*40;
      ((unsigned*)qb)[(h*96 + 91)*8 + off] = 0;
      ((unsigned*)kb)[(h*96 + 91)*8 + off] = 0;
    }
    for (int e = tid; e < 832; e += NT) {
      int r = e / 13, c = e - r*13;
      vtb[r*VTP + 91 + c] = 0;
    }
  }
  __syncthreads();

  // ---- P4: S+P MFMA, all heads: P = exp2(S) bf16 -> pall ----
  {
    const short8 zfrag = {0,0,0,0,0,0,0,0};
    for (int t = wid; t < 144; t += NW) {
      int h = t / 36, r = t - h*36;
      int mt = r / 6, nt = r - mt*6;
      int ar = mt*16 + l15, br = nt*16 + l15;
      short8 a = zfrag, w = zfrag;
      if (lane < 32) {
        a = *(const short8*)(qb + (h*96 + ar)*16 + kfr);
        w = *(const short8*)(kb + (h*96 + br)*16 + kfr);
      }
      f32x4 acc = {0.f,0.f,0.f,0.f};
      acc = __builtin_amdgcn_mfma_f32_16x16x32_bf16(a, w, acc, 0, 0, 0);
      int col = nt*16 + l15;
      #pragma unroll
      for (int i2 = 0; i2 < 4; ++i2) {
        int m = mt*16 + mfr + i2;
        pall[m*PP + h*96 + col] = f2bf(exp2f(acc[i2]));
      }
    }
  }
  __syncthreads();

  // ---- P4b: row sums (j<91) -> linv ; stage out_w -> wAll[0..] swz128 ----
  if (tid < 384) {
    int h = tid / 96, i = tid - h*96;
    const unsigned* p32 = (const unsigned*)(pall + i*PP + h*96);
    float s = 0.f;
    #pragma unroll 5
    for (int jj = 0; jj < 45; ++jj) { unsigned u = p32[jj]; s += bflo(u) + bfhi(u); }
    s += bfs(pall[i*PP + h*96 + 90]);
    linv[tid] = 1.0f / s;
  } else if (tid < 896) {
    int e = tid - 384;                                  // 512 tasks: out_w [64][64]
    int r = e >> 3, c8 = e & 7;
    cp8_swz(wAll, 128, ws + W_OUT, r, c8, 64);
  }
  __syncthreads();

  // ---- P5: PV MFMA (24 tiles, K=96) -> o*linv -> ab16 ; stage ff1 ----
  for (int e = tid; e < 1024; e += NT) {                // ff1 [128][64] -> wAll[4096..]
    int r = e >> 3, c8 = e & 7;
    cp8_swz(wAll + 4096, 128, ws + W_FF1, r, c8, 64);
  }
  for (int t = wid; t < 24; t += NW) {
    int h = t & 3, mt = t >> 2;
    int ar = mt*16 + l15;
    f32x4 acc = {0.f,0.f,0.f,0.f};
    #pragma unroll
    for (int kk = 0; kk < 3; ++kk) {
      int k0 = kk*32 + kfr;
      short8 a = *(const short8*)(pall + ar*PP + h*96 + k0);
      short8 w = *(const short8*)(vtb + (h*16 + l15)*VTP + k0);
      acc = __builtin_amdgcn_mfma_f32_16x16x32_bf16(a, w, acc, 0, 0, 0);
    }
    int col = h*16 + l15;
    #pragma unroll
    for (int i2 = 0; i2 < 4; ++i2) {
      int m = mt*16 + mfr + i2;
      stb16_128(ab16, m, col, acc[i2] * linv[h*96 + m]);
    }
  }
  __syncthreads();

  // ---- P5b: out-proj MFMA: hbuf += o @ out_w^T ; stage ff2 ----
  for (int e = tid; e < 1024; e += NT) {                // ff2 [64][128] -> wAll[12288..] swz256
    int r = e >> 4, c8 = e & 15;
    cp8_swz(wAll + 12288, 256, ws + W_FF2, r, c8, 128);
  }
  for (int t = wid; t < 24; t += NW) {
    int mt = t >> 2, nt = t & 3;
    int ar = mt*16 + l15, br = nt*16 + l15;
    f32x4 acc = {0.f,0.f,0.f,0.f};
    #pragma unroll
    for (int kk = 0; kk < 2; ++kk) {
      short8 a = ldfrag128(ab16, ar, kk*32 + kfr);
      short8 w = ldfrag128(wAll, br, kk*32 + kfr);
      acc = __builtin_amdgcn_mfma_f32_16x16x32_bf16(a, w, acc, 0, 0, 0);
    }
    int col = nt*16 + l15;
    float ob = out_b[col];
    #pragma unroll
    for (int i2 = 0; i2 < 4; ++i2) {
      int m = mt*16 + mfr + i2;
      hbuf[m*HP + col] += acc[i2] + ob;
    }
  }
  __syncthreads();

  // ---- P6: LN2 -> ab16 ----
  ln_group(hbuf, ab16, ln2_g, ln2_b, wid, lane);
  __syncthreads();

  // ---- P7: ff1 MFMA (N=128,K=64) -> f1 bf16 swz256 ----
  for (int t = wid; t < 48; t += NW) {
    int mt = t >> 3, nt = t & 7;
    int ar = mt*16 + l15, br = nt*16 + l15;
    f32x4 acc = {0.f,0.f,0.f,0.f};
    #pragma unroll
    for (int kk = 0; kk < 2; ++kk) {
      short8 a = ldfrag128(ab16,        ar, kk*32 + kfr);
      short8 w = ldfrag128(wAll + 4096, br, kk*32 + kfr);
      acc = __builtin_amdgcn_mfma_f32_16x16x32_bf16(a, w, acc, 0, 0, 0);
    }
    int col = nt*16 + l15;
    float bia = ff1_b[col];
    #pragma unroll
    for (int i2 = 0; i2 < 4; ++i2) {
      int m = mt*16 + mfr + i2;
      *(short*)((char*)f1 + SWZ(m, col, 256)) = f2bf(fmaxf(acc[i2] + bia, 0.f));
    }
  }
  __syncthreads();

  // ---- P8: ff2 MFMA (K=128): ab16 = bf16(h + f1@W^T + b) ; stage from/to ----
  for (int e = tid; e < 1024; e += NT) {                // from/to [128][64] -> wAll[0..] swz128
    int r = e >> 3, c8 = e & 7;
    cp8_swz(wAll, 128, ws + W_FT, r, c8, 64);
  }
  for (int t = wid; t < 24; t += NW) {
    int mt = t >> 2, nt = t & 3;
    int ar = mt*16 + l15, br = nt*16 + l15;
    f32x4 acc = {0.f,0.f,0.f,0.f};
    #pragma unroll
    for (int kk = 0; kk < 4; ++kk) {
      short8 a = ldfrag256(f1,           ar, kk*32 + kfr);
      short8 w = ldfrag256(wAll + 12288, br, kk*32 + kfr);
      acc = __builtin_amdgcn_mfma_f32_16x16x32_bf16(a, w, acc, 0, 0, 0);
    }
    int col = nt*16 + l15;
    float bia = ff2_b[col];
    #pragma unroll
    for (int i2 = 0; i2 < 4; ++i2) {
      int m = mt*16 + mfr + i2;
      stb16_128(ab16, m, col, hbuf[m*HP + col] + acc[i2] + bia);
    }
  }
  __syncthreads();

  // ---- P9: from/to MFMA -> F,T bf16 (alias hbuf) ----
  short* Fb = (short*)hbuf;
  short* Tb = (short*)hbuf + 6144;
  for (int t = wid; t < 48; t += NW) {
    int mt = t >> 3, nt = t & 7;
    int ar = mt*16 + l15, br = nt*16 + l15;
    f32x4 acc = {0.f,0.f,0.f,0.f};
    #pragma unroll
    for (int kk = 0; kk < 2; ++kk) {
      short8 a = ldfrag128(ab16, ar, kk*32 + kfr);
      short8 w = ldfrag128(wAll, br, kk*32 + kfr);
      acc = __builtin_amdgcn_mfma_f32_16x16x32_bf16(a, w, acc, 0, 0, 0);
    }
    int col = nt*16 + l15;
    if (nt < 4) {
      float bia = from_b[col];
      #pragma unroll
      for (int i2 = 0; i2 < 4; ++i2)
        stb16_128(Fb, mt*16 + mfr + i2, col, acc[i2] + bia);
    } else {
      int c2 = col - 64;
      float bia = to_b[c2];
      #pragma unroll
      for (int i2 = 0; i2 < 4; ++i2)
        stb16_128(Tb, mt*16 + mfr + i2, c2, acc[i2] + bia);
    }
  }
  __syncthreads();

  // ---- P10: gram MFMA: G = F @ T^T -> arena fp32 [96][96] ----
  for (int t = wid; t < 36; t += NW) {
    int mt = t / 6, nt = t - mt*6;
    int ar = mt*16 + l15, br = nt*16 + l15;
    f32x4 acc = {0.f,0.f,0.f,0.f};
    #pragma unroll
    for (int kk = 0; kk < 2; ++kk) {
      short8 a = ldfrag128(Fb, ar, kk*32 + kfr);
      short8 w = ldfrag128(Tb, br, kk*32 + kfr);
      acc = __builtin_amdgcn_mfma_f32_16x16x32_bf16(a, w, acc, 0, 0, 0);
    }
    int col = nt*16 + l15;
    #pragma unroll
    for (int i2 = 0; i2 < 4; ++i2)
      G[(mt*16 + mfr + i2)*96 + col] = acc[i2];
  }
  __syncthreads();

  // ---- P11: logits gather ----
  {
    float* ob = out + (size_t)b * NMOV;
    for (int m = tid; m < NMOV; m += NT) {
      ob[m] = G[move_from[m]*96 + move_to[m]] + move_bias[m];
    }
  }
}

extern "C" void kernel_launch(void* const* d_in, const int* in_sizes, int n_in,
                              void* d_out, int out_size, void* d_ws, size_t ws_size,
                              hipStream_t stream) {
  const float* x        = (const float*)d_in[0];
  const float* embed_w  = (const float*)d_in[1];
  const float* embed_b  = (const float*)d_in[2];
  const float* pos      = (const float*)d_in[3];
  const float* in_w     = (const float*)d_in[4];
  const float* in_b     = (const float*)d_in[5];
  const float* out_w    = (const float*)d_in[6];
  const float* out_b    = (const float*)d_in[7];
  const float* ln1_g    = (const float*)d_in[8];
  const float* ln1_b    = (const float*)d_in[9];
  const float* ln2_g    = (const float*)d_in[10];
  const float* ln2_b    = (const float*)d_in[11];
  const float* ff1_w    = (const float*)d_in[12];
  const float* ff1_b    = (const float*)d_in[13];
  const float* ff2_w    = (const float*)d_in[14];
  const float* ff2_b    = (const float*)d_in[15];
  const float* from_w   = (const float*)d_in[16];
  const float* from_b   = (const float*)d_in[17];
  const float* to_w     = (const float*)d_in[18];
  const float* to_b     = (const float*)d_in[19];
  const float* move_bias= (const float*)d_in[20];
  const int*   move_from= (const int*)d_in[21];
  const int*   move_to  = (const int*)d_in[22];

  short* wsb = (short*)d_ws;
  prep_w<<<dim3((W_TOTAL + 255)/256), dim3(256), 0, stream>>>(
      embed_w, in_w, out_w, ff1_w, ff2_w, from_w, to_w, wsb);

  int B = in_sizes[0] / (CIN * 121);
  policy_fused<<<dim3(B), dim3(NT), 0, stream>>>(
      x, embed_b, pos, in_b, out_b,
      ln1_g, ln1_b, ln2_g, ln2_b, ff1_b, ff2_b,
      from_b, to_b, move_bias, move_from, move_to,
      (const short*)wsb, (float*)d_out);
}

// Round 13
// 52.864 us; speedup vs baseline: 1.6629x; 1.0022x over previous
//
#include <hip/hip_runtime.h>
#include <hip/hip_bf16.h>

typedef __attribute__((ext_vector_type(8))) short short8;
typedef __attribute__((ext_vector_type(4))) float f32x4;

#define NC    91
#define DM    64
#define CIN   128
#define NMOV  4206
#define MR    96
#define HP    68      // hbuf fp32 pitch
#define NT    1024
#define NW    16
#define PP    392     // P_all bf16 pitch (shorts): 4 heads * 96 + 8 pad
#define VTP   104     // vT pitch (j dim, shorts)

// d_ws bf16 weight offsets (in shorts)
#define W_EMBED 0
#define W_IN    8192
#define W_OUT   20480
#define W_FF1   24576
#define W_FF2   32768
#define W_FT    40960
#define W_TOTAL 49152

__constant__ int HEXOFF[NC] = {
  55,66,77,88,99,110,
  45,56,67,78,89,100,111,
  35,46,57,68,79,90,101,112,
  25,36,47,58,69,80,91,102,113,
  15,26,37,48,59,70,81,92,103,114,
  5,16,27,38,49,60,71,82,93,104,115,
  6,17,28,39,50,61,72,83,94,105,
  7,18,29,40,51,62,73,84,95,
  8,19,30,41,52,63,74,85,
  9,20,31,42,53,64,75,
  10,21,32,43,54,65
};

#define SWZ(row, col, PB) ((row)*(PB) + ((((((col)*2)>>4)) ^ ((row)&7)) << 4) + (((col)*2)&15))

__device__ __forceinline__ short f2bf(float f) {
  __hip_bfloat16 h = __float2bfloat16(f);
  return __builtin_bit_cast(short, h);
}
__device__ __forceinline__ float bfs(short v) {
  return __builtin_bit_cast(float, ((unsigned)(unsigned short)v) << 16);
}
__device__ __forceinline__ float bflo(unsigned u){ return __builtin_bit_cast(float, u << 16); }
__device__ __forceinline__ float bfhi(unsigned u){ return __builtin_bit_cast(float, u & 0xffff0000u); }

__device__ __forceinline__ short8 ldfrag128(const short* buf, int row, int k0) {
  return *(const short8*)((const char*)buf + SWZ(row, k0, 128));
}
__device__ __forceinline__ short8 ldfrag256(const short* buf, int row, int k0) {
  return *(const short8*)((const char*)buf + SWZ(row, k0, 256));
}
__device__ __forceinline__ void stb16_128(short* buf, int row, int col, float v) {
  *(short*)((char*)buf + SWZ(row, col, 128)) = f2bf(v);
}
// 16B copy from bf16 ws (row-major, K cols) into swizzled LDS slot
__device__ __forceinline__ void cp8_swz(short* dst, int PB, const short* src, int r, int c8, int K) {
  short8 v = *(const short8*)(src + r*K + c8*8);
  *(short8*)((char*)dst + r*PB + ((c8 ^ (r&7)) << 4)) = v;
}

// 16-lane-group LayerNorm -> ab16 bf16 (swz PB=128)
__device__ __forceinline__ void ln_group(const float* hbuf, short* ab16,
                                         const float* gw, const float* gb,
                                         int wid, int lane) {
  const int sub = lane >> 4;
  const int l16 = lane & 15;
  const float4 g4 = *(const float4*)&gw[l16*4];
  const float4 b4 = *(const float4*)&gb[l16*4];
  for (int g = wid; g < 23; g += NW) {
    int i = g*4 + sub;
    if (i < NC) {
      float4 v = *(const float4*)&hbuf[i*HP + l16*4];
      float s  = (v.x + v.y) + (v.z + v.w);
      float sq = fmaf(v.x,v.x, fmaf(v.y,v.y, fmaf(v.z,v.z, v.w*v.w)));
      #pragma unroll
      for (int off = 1; off < 16; off <<= 1) {
        s  += __shfl_xor(s, off, 64);
        sq += __shfl_xor(sq, off, 64);
      }
      float m  = s * (1.0f/64.0f);
      float vr = sq * (1.0f/64.0f) - m*m;
      float rs = rsqrtf(vr + 1e-5f);
      short4 o;
      o.x = f2bf((v.x - m)*rs*g4.x + b4.x);
      o.y = f2bf((v.y - m)*rs*g4.y + b4.y);
      o.z = f2bf((v.z - m)*rs*g4.z + b4.z);
      o.w = f2bf((v.w - m)*rs*g4.w + b4.w);
      *(short4*)((char*)ab16 + i*128 + (((l16>>1) ^ (i&7))<<4) + (l16&1)*8) = o;
    }
  }
}

__global__ __launch_bounds__(256)
void prep_w(const float* __restrict__ embed_w, const float* __restrict__ in_w,
            const float* __restrict__ out_w, const float* __restrict__ ff1_w,
            const float* __restrict__ ff2_w, const float* __restrict__ from_w,
            const float* __restrict__ to_w, short* __restrict__ ws)
{
  int i = blockIdx.x*256 + threadIdx.x;
  if (i >= W_TOTAL) return;
  float v;
  if      (i < 8192)  v = embed_w[i];
  else if (i < 20480) v = in_w[i - 8192];
  else if (i < 24576) v = out_w[i - 20480];
  else if (i < 32768) v = ff1_w[i - 24576];
  else if (i < 40960) v = ff2_w[i - 32768];
  else if (i < 45056) v = from_w[i - 40960];
  else                v = to_w[i - 45056];
  ws[i] = f2bf(v);
}

__global__ __launch_bounds__(1024, 1)
void policy_fused(
    const float* __restrict__ x,
    const float* __restrict__ embed_b, const float* __restrict__ pos,
    const float* __restrict__ in_b,  const float* __restrict__ out_b,
    const float* __restrict__ ln1_g, const float* __restrict__ ln1_b,
    const float* __restrict__ ln2_g, const float* __restrict__ ln2_b,
    const float* __restrict__ ff1_b, const float* __restrict__ ff2_b,
    const float* __restrict__ from_b, const float* __restrict__ to_b,
    const float* __restrict__ move_bias,
    const int* __restrict__ move_from, const int* __restrict__ move_to,
    const short* __restrict__ ws,
    float* __restrict__ out)
{
  __shared__ float arena[18816];     // 75264B: feats / qkv fp32 / P_all / G+f1
  __shared__ float hbuf[MR*HP];      // 26112B: residual h ; F,T alias after P8
  __shared__ short ab16[MR*64];      // 12288B: LN out / attn out
  __shared__ short wAll[20480];      // 40960B: staged weights / qf,kf,vtb
  __shared__ float linv[384];        // 1536B       => total 156160B

  const int tid  = threadIdx.x;
  const int lane = tid & 63;
  const int wid  = tid >> 6;
  const int l15  = lane & 15;
  const int kfr  = (lane >> 4) * 8;
  const int mfr  = (lane >> 4) * 4;
  const int b    = blockIdx.x;
  const float* xb = x + (size_t)b * (CIN*121);

  short* featsb = (short*)arena;           // [96][128] bf16 swz PB=256
  float* qkv    = arena;                   // [96][196] fp32 (after feats dead)
  short* pall   = (short*)arena;           // [96][PP] bf16 (after qkv dead)
  float* G      = arena;                   // [96][96] fp32 (after pall dead)
  short* f1     = (short*)arena + 18432;   // [96][128] bf16 swz256 (bytes 36864..61440)
  short* qf     = wAll;                    // frag-linear q: [4][6][32][8]  (6144 shorts)
  short* kf     = wAll + 6144;             // frag-linear k: [4][6][32][8]
  short* vtb    = wAll + 12288;            // [4][16][VTP] bf16 (V^T)

  // ---- P0: hex-gather feats -> bf16 ; stage embed_w + in_w from ws ----
  for (int e = tid; e < 16*NC; e += NT) {
    int c0 = e / NC, i = e - c0*NC;
    float v[8];
    #pragma unroll
    for (int u = 0; u < 8; ++u) v[u] = xb[(c0*8 + u)*121 + HEXOFF[i]];
    short8 s8;
    #pragma unroll
    for (int u = 0; u < 8; ++u) s8[u] = f2bf(v[u]);
    *(short8*)((char*)featsb + i*256 + ((c0 ^ (i&7)) << 4)) = s8;
  }
  if (tid < 320) ((unsigned*)featsb)[5824 + tid] = 0;   // zero feats rows 91..95
  for (int e = tid; e < 1024; e += NT) {                // embed_w [64][128] -> wAll swz256
    int r = e >> 4, c8 = e & 15;
    cp8_swz(wAll, 256, ws + W_EMBED, r, c8, 128);
  }
  for (int e = tid; e < 1536; e += NT) {                // in_w [192][64] -> wAll+8192 swz128
    int r = e >> 3, c8 = e & 7;
    cp8_swz(wAll + 8192, 128, ws + W_IN, r, c8, 64);
  }
  __syncthreads();

  // ---- P1: embed MFMA (K=128) -> hbuf ----
  for (int t = wid; t < 24; t += NW) {
    int mt = t >> 2, nt = t & 3;
    int ar = mt*16 + l15, br = nt*16 + l15;
    f32x4 acc = {0.f,0.f,0.f,0.f};
    #pragma unroll
    for (int kk = 0; kk < 4; ++kk) {
      short8 a = ldfrag256(featsb, ar, kk*32 + kfr);
      short8 w = ldfrag256(wAll,   br, kk*32 + kfr);
      acc = __builtin_amdgcn_mfma_f32_16x16x32_bf16(a, w, acc, 0, 0, 0);
    }
    int col = nt*16 + l15;
    float eb = embed_b[col];
    #pragma unroll
    for (int i2 = 0; i2 < 4; ++i2) {
      int m = mt*16 + mfr + i2;
      float p = (m < NC) ? pos[m*DM + col] : 0.f;
      hbuf[m*HP + col] = acc[i2] + eb + p;
    }
  }
  __syncthreads();

  // ---- P2: zero ab16 tail + LN1 -> ab16 ----
  if (tid < 160) ((unsigned*)ab16)[2912 + tid] = 0;
  ln_group(hbuf, ab16, ln1_g, ln1_b, wid, lane);
  __syncthreads();

  // ---- P3: qkv MFMA (N=192,K=64) -> qkv fp32 arena pitch 196 ----
  for (int t = wid; t < 72; t += NW) {
    int mt = t / 12, nt = t - mt*12;
    int ar = mt*16 + l15, br = nt*16 + l15;
    f32x4 acc = {0.f,0.f,0.f,0.f};
    #pragma unroll
    for (int kk = 0; kk < 2; ++kk) {
      short8 a = ldfrag128(ab16,        ar, kk*32 + kfr);
      short8 w = ldfrag128(wAll + 8192, br, kk*32 + kfr);
      acc = __builtin_amdgcn_mfma_f32_16x16x32_bf16(a, w, acc, 0, 0, 0);
    }
    int col = nt*16 + l15;
    float bia = in_b[col];
    #pragma unroll
    for (int i2 = 0; i2 < 4; ++i2)
      qkv[(mt*16 + mfr + i2)*196 + col] = acc[i2] + bia;
  }
  __syncthreads();

  // ---- P3b: qkv fp32 -> frag-linear qf(*CS), kf ; vtb transposed ; tails ----
  {
    const float CS = 0.25f * 1.4426950408889634f;
    if (tid < 4*NC) {
      int h = tid / NC, i = tid - h*NC;
      const float* src = &qkv[i*196];
      short8 qs0, qs1, ks0, ks1;
      #pragma unroll
      for (int d = 0; d < 8; ++d) {
        qs0[d] = f2bf(src[h*16 + d] * CS);      ks0[d] = f2bf(src[64 + h*16 + d]);
        qs1[d] = f2bf(src[h*16 + 8 + d] * CS);  ks1[d] = f2bf(src[64 + h*16 + 8 + d]);
      }
      int base = ((h*6 + (i>>4))*32 + (i&15))*8;
      *(short8*)(qf + base)       = qs0;   // lane = (i&15), k-group 0
      *(short8*)(qf + base + 128) = qs1;   // lane = 16 + (i&15), k-group 1
      *(short8*)(kf + base)       = ks0;
      *(short8*)(kf + base + 128) = ks1;
      #pragma unroll
      for (int d = 0; d < 16; ++d)
        vtb[(h*16 + d)*VTP + i] = f2bf(src[128 + h*16 + d]);
    }
    // zero frag slots for rows i=91..95 (tile it=5, lanes g*16+11..15) — disjoint from writes
    for (int e = tid; e < 320; e += NT) {
      int w = e & 3, r = e >> 2;
      int l5 = r % 5; r /= 5;
      int g = r & 1; r >>= 1;
      int buf = r & 1; int h = r >> 1;
      unsigned* dst = (unsigned*)((buf ? kf : qf) + ((h*6 + 5)*32 + g*16 + 11 + l5)*8);
      dst[w] = 0;
    }
    // zero vT cols 91..103
    for (int e = tid; e < 832; e += NT) {
      int r = e / 13, c = e - r*13;
      vtb[r*VTP + 91 + c] = 0;
    }
  }
  __syncthreads();

  // ---- P4: S MFMA (swapped: A=kf, B=qf) -> P = exp2(S) bf16, short4 stores ----
  {
    const short8 zfrag = {0,0,0,0,0,0,0,0};
    for (int t = wid; t < 144; t += NW) {
      int h = t / 36, r = t - h*36;
      int it = r / 6, jt = r - it*6;
      short8 a = zfrag, w = zfrag;
      if (lane < 32) {
        a = *(const short8*)(kf + ((h*6 + jt)*32 + lane)*8);  // A row = j
        w = *(const short8*)(qf + ((h*6 + it)*32 + lane)*8);  // B row = i
      }
      f32x4 acc = {0.f,0.f,0.f,0.f};
      acc = __builtin_amdgcn_mfma_f32_16x16x32_bf16(a, w, acc, 0, 0, 0);
      // C[j][i]: col=l15 -> i, rows mfr+i2 -> j (4 consecutive j)
      int i = it*16 + l15;
      short4 p4;
      p4.x = f2bf(exp2f(acc[0]));
      p4.y = f2bf(exp2f(acc[1]));
      p4.z = f2bf(exp2f(acc[2]));
      p4.w = f2bf(exp2f(acc[3]));
      *(short4*)(pall + i*PP + h*96 + jt*16 + mfr) = p4;
    }
  }
  __syncthreads();

  // ---- P4b: row sums (j<91) -> linv ; stage out_w -> wAll[0..] swz128 ----
  if (tid < 384) {
    int h = tid / 96, i = tid - h*96;
    const unsigned* p32 = (const unsigned*)(pall + i*PP + h*96);
    float s = 0.f;
    #pragma unroll 5
    for (int jj = 0; jj < 45; ++jj) { unsigned u = p32[jj]; s += bflo(u) + bfhi(u); }
    s += bfs(pall[i*PP + h*96 + 90]);
    linv[tid] = 1.0f / s;
  } else if (tid < 896) {
    int e = tid - 384;                                  // 512 tasks: out_w [64][64]
    int r = e >> 3, c8 = e & 7;
    cp8_swz(wAll, 128, ws + W_OUT, r, c8, 64);
  }
  __syncthreads();

  // ---- P5: PV MFMA (swapped: A=vtb, B=pall) -> o*linv -> ab16 short4 ; stage ff1 ----
  for (int e = tid; e < 1024; e += NT) {                // ff1 [128][64] -> wAll+4096
    int r = e >> 3, c8 = e & 7;
    cp8_swz(wAll + 4096, 128, ws + W_FF1, r, c8, 64);
  }
  for (int t = wid; t < 24; t += NW) {
    int h = t & 3, it = t >> 2;
    f32x4 acc = {0.f,0.f,0.f,0.f};
    #pragma unroll
    for (int kk = 0; kk < 3; ++kk) {
      int k0 = kk*32 + kfr;
      short8 a = *(const short8*)(vtb + (h*16 + l15)*VTP + k0);        // A row = d
      short8 w = *(const short8*)(pall + (it*16 + l15)*PP + h*96 + k0); // B row = i
      acc = __builtin_amdgcn_mfma_f32_16x16x32_bf16(a, w, acc, 0, 0, 0);
    }
    // C[d][i]: col=l15 -> i, rows mfr+i2 -> d (4 consecutive d)
    int i = it*16 + l15;
    float li = linv[h*96 + i];
    short4 o4;
    o4.x = f2bf(acc[0] * li);
    o4.y = f2bf(acc[1] * li);
    o4.z = f2bf(acc[2] * li);
    o4.w = f2bf(acc[3] * li);
    *(short4*)((char*)ab16 + SWZ(i, h*16 + mfr, 128)) = o4;
  }
  __syncthreads();

  // ---- P5b: out-proj MFMA: hbuf += o @ out_w^T ; stage ff2 ----
  for (int e = tid; e < 1024; e += NT) {                // ff2 [64][128] -> wAll+12288 swz256
    int r = e >> 4, c8 = e & 15;
    cp8_swz(wAll + 12288, 256, ws + W_FF2, r, c8, 128);
  }
  for (int t = wid; t < 24; t += NW) {
    int mt = t >> 2, nt = t & 3;
    int ar = mt*16 + l15, br = nt*16 + l15;
    f32x4 acc = {0.f,0.f,0.f,0.f};
    #pragma unroll
    for (int kk = 0; kk < 2; ++kk) {
      short8 a = ldfrag128(ab16, ar, kk*32 + kfr);
      short8 w = ldfrag128(wAll, br, kk*32 + kfr);
      acc = __builtin_amdgcn_mfma_f32_16x16x32_bf16(a, w, acc, 0, 0, 0);
    }
    int col = nt*16 + l15;
    float ob = out_b[col];
    #pragma unroll
    for (int i2 = 0; i2 < 4; ++i2) {
      int m = mt*16 + mfr + i2;
      hbuf[m*HP + col] += acc[i2] + ob;
    }
  }
  __syncthreads();

  // ---- P6: LN2 -> ab16 ----
  ln_group(hbuf, ab16, ln2_g, ln2_b, wid, lane);
  __syncthreads();

  // ---- P7: ff1 MFMA (N=128,K=64) -> f1 bf16 swz256 ----
  for (int t = wid; t < 48; t += NW) {
    int mt = t >> 3, nt = t & 7;
    int ar = mt*16 + l15, br = nt*16 + l15;
    f32x4 acc = {0.f,0.f,0.f,0.f};
    #pragma unroll
    for (int kk = 0; kk < 2; ++kk) {
      short8 a = ldfrag128(ab16,        ar, kk*32 + kfr);
      short8 w = ldfrag128(wAll + 4096, br, kk*32 + kfr);
      acc = __builtin_amdgcn_mfma_f32_16x16x32_bf16(a, w, acc, 0, 0, 0);
    }
    int col = nt*16 + l15;
    float bia = ff1_b[col];
    #pragma unroll
    for (int i2 = 0; i2 < 4; ++i2) {
      int m = mt*16 + mfr + i2;
      *(short*)((char*)f1 + SWZ(m, col, 256)) = f2bf(fmaxf(acc[i2] + bia, 0.f));
    }
  }
  __syncthreads();

  // ---- P8: ff2 MFMA (K=128): ab16 = bf16(h + f1@W^T + b) ; stage from/to ----
  for (int e = tid; e < 1024; e += NT) {                // from/to [128][64] -> wAll swz128
    int r = e >> 3, c8 = e & 7;
    cp8_swz(wAll, 128, ws + W_FT, r, c8, 64);
  }
  for (int t = wid; t < 24; t += NW) {
    int mt = t >> 2, nt = t & 3;
    int ar = mt*16 + l15, br = nt*16 + l15;
    f32x4 acc = {0.f,0.f,0.f,0.f};
    #pragma unroll
    for (int kk = 0; kk < 4; ++kk) {
      short8 a = ldfrag256(f1,           ar, kk*32 + kfr);
      short8 w = ldfrag256(wAll + 12288, br, kk*32 + kfr);
      acc = __builtin_amdgcn_mfma_f32_16x16x32_bf16(a, w, acc, 0, 0, 0);
    }
    int col = nt*16 + l15;
    float bia = ff2_b[col];
    #pragma unroll
    for (int i2 = 0; i2 < 4; ++i2) {
      int m = mt*16 + mfr + i2;
      stb16_128(ab16, m, col, hbuf[m*HP + col] + acc[i2] + bia);
    }
  }
  __syncthreads();

  // ---- P9: from/to MFMA -> F,T bf16 (alias hbuf) ----
  short* Fb = (short*)hbuf;
  short* Tb = (short*)hbuf + 6144;
  for (int t = wid; t < 48; t += NW) {
    int mt = t >> 3, nt = t & 7;
    int ar = mt*16 + l15, br = nt*16 + l15;
    f32x4 acc = {0.f,0.f,0.f,0.f};
    #pragma unroll
    for (int kk = 0; kk < 2; ++kk) {
      short8 a = ldfrag128(ab16, ar, kk*32 + kfr);
      short8 w = ldfrag128(wAll, br, kk*32 + kfr);
      acc = __builtin_amdgcn_mfma_f32_16x16x32_bf16(a, w, acc, 0, 0, 0);
    }
    int col = nt*16 + l15;
    if (nt < 4) {
      float bia = from_b[col];
      #pragma unroll
      for (int i2 = 0; i2 < 4; ++i2)
        stb16_128(Fb, mt*16 + mfr + i2, col, acc[i2] + bia);
    } else {
      int c2 = col - 64;
      float bia = to_b[c2];
      #pragma unroll
      for (int i2 = 0; i2 < 4; ++i2)
        stb16_128(Tb, mt*16 + mfr + i2, c2, acc[i2] + bia);
    }
  }
  __syncthreads();

  // ---- P10: gram MFMA: G = F @ T^T -> arena fp32 [96][96] ----
  for (int t = wid; t < 36; t += NW) {
    int mt = t / 6, nt = t - mt*6;
    int ar = mt*16 + l15, br = nt*16 + l15;
    f32x4 acc = {0.f,0.f,0.f,0.f};
    #pragma unroll
    for (int kk = 0; kk < 2; ++kk) {
      short8 a = ldfrag128(Fb, ar, kk*32 + kfr);
      short8 w = ldfrag128(Tb, br, kk*32 + kfr);
      acc = __builtin_amdgcn_mfma_f32_16x16x32_bf16(a, w, acc, 0, 0, 0);
    }
    int col = nt*16 + l15;
    #pragma unroll
    for (int i2 = 0; i2 < 4; ++i2)
      G[(mt*16 + mfr + i2)*96 + col] = acc[i2];
  }
  __syncthreads();

  // ---- P11: logits gather ----
  {
    float* ob = out + (size_t)b * NMOV;
    for (int m = tid; m < NMOV; m += NT) {
      ob[m] = G[move_from[m]*96 + move_to[m]] + move_bias[m];
    }
  }
}

extern "C" void kernel_launch(void* const* d_in, const int* in_sizes, int n_in,
                              void* d_out, int out_size, void* d_ws, size_t ws_size,
                              hipStream_t stream) {
  const float* x        = (const float*)d_in[0];
  const float* embed_w  = (const float*)d_in[1];
  const float* embed_b  = (const float*)d_in[2];
  const float* pos      = (const float*)d_in[3];
  const float* in_w     = (const float*)d_in[4];
  const float* in_b     = (const float*)d_in[5];
  const float* out_w    = (const float*)d_in[6];
  const float* out_b    = (const float*)d_in[7];
  const float* ln1_g    = (const float*)d_in[8];
  const float* ln1_b    = (const float*)d_in[9];
  const float* ln2_g    = (const float*)d_in[10];
  const float* ln2_b    = (const float*)d_in[11];
  const float* ff1_w    = (const float*)d_in[12];
  const float* ff1_b    = (const float*)d_in[13];
  const float* ff2_w    = (const float*)d_in[14];
  const float* ff2_b    = (const float*)d_in[15];
  const float* from_w   = (const float*)d_in[16];
  const float* from_b   = (const float*)d_in[17];
  const float* to_w     = (const float*)d_in[18];
  const float* to_b     = (const float*)d_in[19];
  const float* move_bias= (const float*)d_in[20];
  const int*   move_from= (const int*)d_in[21];
  const int*   move_to  = (const int*)d_in[22];

  short* wsb = (short*)d_ws;
  prep_w<<<dim3((W_TOTAL + 255)/256), dim3(256), 0, stream>>>(
      embed_w, in_w, out_w, ff1_w, ff2_w, from_w, to_w, wsb);

  int B = in_sizes[0] / (CIN * 121);
  policy_fused<<<dim3(B), dim3(NT), 0, stream>>>(
      x, embed_b, pos, in_b, out_b,
      ln1_g, ln1_b, ln2_g, ln2_b, ff1_b, ff2_b,
      from_b, to_b, move_bias, move_from, move_to,
      (const short*)wsb, (float*)d_out);
}